// Round 1
// baseline (242.438 us; speedup 1.0000x reference)
//
#include <hip/hip_runtime.h>
#include <stdint.h>

#define EPS 1e-3f

typedef __bf16 bf16x8 __attribute__((ext_vector_type(8)));
typedef float  f32x4  __attribute__((ext_vector_type(4)));

static __device__ __forceinline__ uint16_t f2bf(float f) {
  union { float f; uint32_t u; } v; v.f = f;
  uint32_t u = v.u;
  uint32_t r = u + 0x7fffu + ((u >> 16) & 1u);   // RNE
  return (uint16_t)(r >> 16);
}

static __device__ __forceinline__ void gload_lds16(const void* g, void* l) {
  __builtin_amdgcn_global_load_lds(
      (const __attribute__((address_space(1))) unsigned int*)g,
      (__attribute__((address_space(3))) unsigned int*)l,
      16, 0, 0);
}

// ---------------------------------------------------------------------------
// Kernel 1: projections + BN(q,v) + softmax(k).  x:[16384][256]
// Qf:[16384][64], Ksm:[16384][16], Vf:[16384][64]
// ---------------------------------------------------------------------------
__global__ __launch_bounds__(256) void proj_kernel(
    const float* __restrict__ x, const float* __restrict__ Wq,
    const float* __restrict__ Wk, const float* __restrict__ Wv,
    const float* __restrict__ gq, const float* __restrict__ bq,
    const float* __restrict__ mq, const float* __restrict__ vq,
    const float* __restrict__ gv, const float* __restrict__ bv,
    const float* __restrict__ mv, const float* __restrict__ vvp,
    float* __restrict__ Qf, float* __restrict__ Ksm, float* __restrict__ Vf)
{
  __shared__ float xs[16][256];
  const int t = threadIdx.x;
  const int r0 = blockIdx.x * 16;
#pragma unroll
  for (int it = 0; it < 4; ++it) {
    int off = it * 1024 + t * 4;
    int row = off >> 8, col = off & 255;
    *(float4*)&xs[row][col] = *(const float4*)&x[(r0 + row) * 256 + col];
  }
  __syncthreads();
  const int row_l = t >> 4, ci = t & 15;
  const float* xr = xs[row_l];
  float acc[9];
#pragma unroll
  for (int j = 0; j < 9; ++j) acc[j] = 0.f;
  for (int m = 0; m < 256; ++m) {
    float xv = xr[m];
#pragma unroll
    for (int j = 0; j < 4; ++j) acc[j]     = fmaf(xv, Wq[m * 64 + ci + 16 * j], acc[j]);
    acc[4] = fmaf(xv, Wk[m * 16 + ci], acc[4]);
#pragma unroll
    for (int j = 0; j < 4; ++j) acc[5 + j] = fmaf(xv, Wv[m * 64 + ci + 16 * j], acc[5 + j]);
  }
  const int r = r0 + row_l;
  // q with BN
#pragma unroll
  for (int j = 0; j < 4; ++j) {
    int c = ci + 16 * j;
    float s = gq[c] * rsqrtf(vq[c] + EPS);
    Qf[r * 64 + c] = (acc[j] - mq[c]) * s + bq[c];
  }
  // k softmax across the 16 channels (held by the 16 lanes of this row group)
  {
    float kv = acc[4];
    float mx = kv;
#pragma unroll
    for (int d = 1; d < 16; d <<= 1) mx = fmaxf(mx, __shfl_xor(mx, d, 64));
    float e = __expf(kv - mx);
    float sm = e;
#pragma unroll
    for (int d = 1; d < 16; d <<= 1) sm += __shfl_xor(sm, d, 64);
    Ksm[r * 16 + ci] = e / sm;
  }
  // v with BN
#pragma unroll
  for (int j = 0; j < 4; ++j) {
    int c = ci + 16 * j;
    float s = gv[c] * rsqrtf(vvp[c] + EPS);
    Vf[r * 64 + c] = (acc[5 + j] - mv[c]) * s + bv[c];
  }
}

// ---------------------------------------------------------------------------
// Kernel 2: E convert+transpose.  E:[n][m][16] f32 -> Ebf:[n*16+k][m] bf16
// ---------------------------------------------------------------------------
__global__ __launch_bounds__(256) void econv(const float* __restrict__ E,
                                             uint16_t* __restrict__ Ebf)
{
  const int n = blockIdx.x, t = threadIdx.x;
  const float* En = E + (size_t)n * 16384;
#pragma unroll 1
  for (int kq = 0; kq < 4; ++kq) {
#pragma unroll
    for (int mi = 0; mi < 4; ++mi) {
      int m = mi * 256 + t;
      float4 d = *(const float4*)&En[m * 16 + kq * 4];
      const float* dp = (const float*)&d;
#pragma unroll
      for (int j = 0; j < 4; ++j) {
        int k = kq * 4 + j;
        Ebf[(size_t)(n * 16 + k) * 1024 + m] = f2bf(dp[j]);
      }
    }
  }
}

// ---------------------------------------------------------------------------
// Kernel 3: V transpose+convert.  Vf:[b*1024+m][64] -> VbfT:[b*64+v][1024 m]
// grid (16 b, 16 m-chunks)
// ---------------------------------------------------------------------------
__global__ __launch_bounds__(256) void transpose_v(const float* __restrict__ Vf,
                                                   uint16_t* __restrict__ VbfT)
{
  __shared__ float tile[64][65];
  const int b = blockIdx.x, mc = blockIdx.y, t = threadIdx.x;
  const int m0 = mc * 64;
#pragma unroll
  for (int it = 0; it < 4; ++it) {
    int off = it * 1024 + t * 4;
    int ml = off >> 6, v = off & 63;
    float4 d = *(const float4*)&Vf[(size_t)(b * 1024 + m0 + ml) * 64 + v];
    tile[ml][v + 0] = d.x; tile[ml][v + 1] = d.y;
    tile[ml][v + 2] = d.z; tile[ml][v + 3] = d.w;
  }
  __syncthreads();
  const int v = t >> 2, sg = t & 3;
  union { uint16_t u16[16]; uint4 u4[2]; } pk;
#pragma unroll
  for (int i = 0; i < 16; ++i) pk.u16[i] = f2bf(tile[sg * 16 + i][v]);
  uint4* dst = (uint4*)&VbfT[(size_t)(b * 64 + v) * 1024 + m0 + sg * 16];
  dst[0] = pk.u4[0]; dst[1] = pk.u4[1];
}

// ---------------------------------------------------------------------------
// Kernel 4: lam_c[b][k][v] = sum_m Ksm[b,m,k] * Vf[b,m,v]   (fp32)
// ---------------------------------------------------------------------------
__global__ __launch_bounds__(256) void lamc_kernel(const float* __restrict__ Ksm,
                                                   const float* __restrict__ Vf,
                                                   float* __restrict__ Lc)
{
  __shared__ float ks[1024][16];   // 64KB
  const int b = blockIdx.x, t = threadIdx.x;
  const float4* src = (const float4*)(Ksm + (size_t)b * 16384);
  float4* dst = (float4*)ks;
#pragma unroll
  for (int it = 0; it < 16; ++it) dst[it * 256 + t] = src[it * 256 + t];
  __syncthreads();
  const int v = t & 63, kq = t >> 6;
  float acc[4] = {0.f, 0.f, 0.f, 0.f};
  for (int m = 0; m < 1024; ++m) {
    float vv = Vf[(size_t)(b * 1024 + m) * 64 + v];
#pragma unroll
    for (int i = 0; i < 4; ++i) acc[i] = fmaf(ks[m][kq * 4 + i], vv, acc[i]);
  }
#pragma unroll
  for (int i = 0; i < 4; ++i)
    Lc[(size_t)(b * 16 + kq * 4 + i) * 64 + v] = acc[i];
}

// ---------------------------------------------------------------------------
// Kernel 5: GEMM  C[row=n*16+k][col=b*64+v] = Ebf[row][:] . VbfT[col][:]
// + fused epilogue: out[b,n,h*64+v] = sum_k Qf[b,n,h*16+k]*(Lc[b,k,v]+C[row][col])
// 128x128 tile, BK=64, 4 waves in 2x2 grid, XOR-swizzled LDS.
// ---------------------------------------------------------------------------
__global__ __launch_bounds__(256) void gemm_out(
    const uint16_t* __restrict__ Ebf,   // [16384][1024]
    const uint16_t* __restrict__ VbfT,  // [1024][1024]
    const float* __restrict__ Qf,       // [16384][64]
    const float* __restrict__ Lc,       // [16][16][64]
    float* __restrict__ out)            // [16384][256]
{
  __shared__ __align__(16) char smem[33024];
  uint16_t* As = (uint16_t*)smem;             // [128 rows][64 k] bf16, swizzled
  uint16_t* Bs = (uint16_t*)(smem + 16384);   // [128 cols][64 k] bf16, swizzled
  float (*Cs)[129] = (float (*)[129])smem;    // epilogue: [64][129] f32

  const int t = threadIdx.x;
  const int wid = t >> 6, lane = t & 63;
  const int rb = blockIdx.x >> 3, cb = blockIdx.x & 7;
  const int row0 = rb * 128;
  const int col0 = cb * 128;
  const int wm = wid >> 1, wn = wid & 1;

  f32x4 acc[4][4];
#pragma unroll
  for (int i = 0; i < 4; ++i)
#pragma unroll
    for (int j = 0; j < 4; ++j) acc[i][j] = f32x4{0.f, 0.f, 0.f, 0.f};

  const uint16_t* Abase = Ebf + (size_t)row0 * 1024;
  const uint16_t* Bbase = VbfT + (size_t)col0 * 1024;

#pragma unroll 1
  for (int ksx = 0; ksx < 16; ++ksx) {
    const int m0 = ksx * 64;
    // stage A and B tiles: linear LDS dest, inverse-swizzled global source
#pragma unroll
    for (int it = 0; it < 4; ++it) {
      int idx = it * 256 + t;
      int row = idx >> 3, seg = idx & 7;
      int sseg = seg ^ (row & 7);
      gload_lds16(Abase + (size_t)row * 1024 + m0 + sseg * 8, (char*)As + idx * 16);
      gload_lds16(Bbase + (size_t)row * 1024 + m0 + sseg * 8, (char*)Bs + idx * 16);
    }
    __syncthreads();
#pragma unroll
    for (int kk = 0; kk < 2; ++kk) {
      bf16x8 a[4], b[4];
      const int s = kk * 4 + (lane >> 4);
#pragma unroll
      for (int i = 0; i < 4; ++i) {
        int row = wm * 64 + i * 16 + (lane & 15);
        a[i] = *(const bf16x8*)((const char*)As + row * 128 + (s ^ (row & 7)) * 16);
      }
#pragma unroll
      for (int j = 0; j < 4; ++j) {
        int row = wn * 64 + j * 16 + (lane & 15);
        b[j] = *(const bf16x8*)((const char*)Bs + row * 128 + (s ^ (row & 7)) * 16);
      }
#pragma unroll
      for (int i = 0; i < 4; ++i)
#pragma unroll
        for (int j = 0; j < 4; ++j)
          acc[i][j] = __builtin_amdgcn_mfma_f32_16x16x32_bf16(a[i], b[j], acc[i][j], 0, 0, 0);
    }
    __syncthreads();
  }

  // fused epilogue, two 64-row phases
  const int n0 = row0 >> 4;   // 8 n per block
  const int b0 = col0 >> 6;   // 2 b per block
#pragma unroll 1
  for (int ph = 0; ph < 2; ++ph) {
    if (wm == ph) {
#pragma unroll
      for (int i = 0; i < 4; ++i) {
        int rloc = i * 16 + ((lane >> 4) << 2);
#pragma unroll
        for (int j = 0; j < 4; ++j) {
          int col = wn * 64 + j * 16 + (lane & 15);
          int bb = b0 + (col >> 6), v = col & 63;
#pragma unroll
          for (int r = 0; r < 4; ++r) {
            int k = (rloc + r) & 15;
            Cs[rloc + r][col] = acc[i][j][r] + Lc[(size_t)((bb << 4) + k) * 64 + v];
          }
        }
      }
    }
    __syncthreads();
    {
      const int v = t & 63, g = t >> 6;
#pragma unroll
      for (int c = 0; c < 8; ++c) {
        int combo = g + (c << 2);        // 0..31
        int n_l = combo >> 3;
        int b_l = (combo >> 2) & 1;
        int h   = combo & 3;
        int n = n0 + (ph << 2) + n_l;
        int bb = b0 + b_l;
        const float* qp = &Qf[(size_t)((bb << 10) + n) * 64 + (h << 4)];
        float s = 0.f;
#pragma unroll
        for (int k = 0; k < 16; ++k)
          s = fmaf(qp[k], Cs[(n_l << 4) + k][(b_l << 6) + v], s);
        out[((size_t)((bb << 10) + n) << 8) + (h << 6) + v] = s;
      }
    }
    __syncthreads();
  }
}

// ---------------------------------------------------------------------------
extern "C" void kernel_launch(void* const* d_in, const int* in_sizes, int n_in,
                              void* d_out, int out_size, void* d_ws, size_t ws_size,
                              hipStream_t stream) {
  const float* x   = (const float*)d_in[0];
  const float* Wq  = (const float*)d_in[1];
  const float* Wk  = (const float*)d_in[2];
  const float* Wv  = (const float*)d_in[3];
  const float* gq  = (const float*)d_in[4];
  const float* bq  = (const float*)d_in[5];
  const float* mq  = (const float*)d_in[6];
  const float* vq  = (const float*)d_in[7];
  const float* gv  = (const float*)d_in[8];
  const float* bv  = (const float*)d_in[9];
  const float* mv  = (const float*)d_in[10];
  const float* vvp = (const float*)d_in[11];
  const float* E   = (const float*)d_in[12];
  float* out = (float*)d_out;

  char* ws = (char*)d_ws;
  uint16_t* Ebf  = (uint16_t*)(ws);                 // 33,554,432 B
  uint16_t* VbfT = (uint16_t*)(ws + 33554432);      //  2,097,152 B
  float*    Qf   = (float*)(ws + 35651584);         //  4,194,304 B
  float*    Ksm  = (float*)(ws + 39845888);         //  1,048,576 B
  float*    Vf   = (float*)(ws + 40894464);         //  4,194,304 B
  float*    Lc   = (float*)(ws + 45088768);         //     65,536 B

  hipLaunchKernelGGL(econv,       dim3(1024),    dim3(256), 0, stream, E, Ebf);
  hipLaunchKernelGGL(proj_kernel, dim3(1024),    dim3(256), 0, stream, x, Wq, Wk, Wv,
                     gq, bq, mq, vq, gv, bv, mv, vvp, Qf, Ksm, Vf);
  hipLaunchKernelGGL(transpose_v, dim3(16, 16),  dim3(256), 0, stream, Vf, VbfT);
  hipLaunchKernelGGL(lamc_kernel, dim3(16),      dim3(256), 0, stream, Ksm, Vf, Lc);
  hipLaunchKernelGGL(gemm_out,    dim3(1024),    dim3(256), 0, stream, Ebf, VbfT, Qf, Lc, out);
}